// Round 1
// baseline (1013.096 us; speedup 1.0000x reference)
//
#include <hip/hip_runtime.h>

// KroneckerLinear: out[n][8*j1+j2] = bias + sum_{i1,i2} x[n][8*i1+i2]*f1[j1][i1]*f2[j2][i2]
// Factored per-row as O = f1 · X · f2^T  (X = row viewed 8x8): 1024 MACs/row
// instead of 4096. Memory-bound: 1.07 GB traffic @ ~6.3 TB/s -> ~170 us floor.
// One thread per row; factors/bias are wave-uniform -> scalar loads (SGPRs).

__global__ __launch_bounds__(256) void kron_linear_kernel(
    const float* __restrict__ x,
    const float* __restrict__ f1,
    const float* __restrict__ f2,
    const float* __restrict__ bias,
    float* __restrict__ out,
    int n_rows)
{
    int row = blockIdx.x * 256 + threadIdx.x;
    if (row >= n_rows) return;

    const float* xr = x + (size_t)row * 64;
    float* orow = out + (size_t)row * 64;

    // Phase 1: T[i1][j2] = sum_i2 X[i1][i2] * f2[j2][i2]
    float T[8][8];
#pragma unroll
    for (int i1 = 0; i1 < 8; ++i1) {
        float4 a = *(const float4*)(xr + i1 * 8);
        float4 b = *(const float4*)(xr + i1 * 8 + 4);
        float xv[8] = {a.x, a.y, a.z, a.w, b.x, b.y, b.z, b.w};
#pragma unroll
        for (int j2 = 0; j2 < 8; ++j2) {
            float acc = 0.f;
#pragma unroll
            for (int i2 = 0; i2 < 8; ++i2)
                acc += xv[i2] * f2[j2 * 8 + i2];
            T[i1][j2] = acc;
        }
    }

    // Phase 2: O[j1][j2] = bias[8*j1+j2] + sum_i1 f1[j1][i1] * T[i1][j2]
#pragma unroll
    for (int j1 = 0; j1 < 8; ++j1) {
        float o[8];
#pragma unroll
        for (int j2 = 0; j2 < 8; ++j2) o[j2] = bias[j1 * 8 + j2];
#pragma unroll
        for (int i1 = 0; i1 < 8; ++i1) {
            float w = f1[j1 * 8 + i1];
#pragma unroll
            for (int j2 = 0; j2 < 8; ++j2)
                o[j2] += w * T[i1][j2];
        }
        float4 s0 = {o[0], o[1], o[2], o[3]};
        float4 s1 = {o[4], o[5], o[6], o[7]};
        *(float4*)(orow + j1 * 8)     = s0;
        *(float4*)(orow + j1 * 8 + 4) = s1;
    }
}

extern "C" void kernel_launch(void* const* d_in, const int* in_sizes, int n_in,
                              void* d_out, int out_size, void* d_ws, size_t ws_size,
                              hipStream_t stream) {
    const float* x    = (const float*)d_in[0];
    const float* f1   = (const float*)d_in[1];
    const float* f2   = (const float*)d_in[2];
    const float* bias = (const float*)d_in[3];
    float* out = (float*)d_out;

    int n_rows = out_size / 64;
    int blocks = (n_rows + 255) / 256;
    kron_linear_kernel<<<blocks, 256, 0, stream>>>(x, f1, f2, bias, out, n_rows);
}